// Round 1
// baseline (53.139 us; speedup 1.0000x reference)
//
#include <hip/hip_runtime.h>
#include <hip/hip_bf16.h>
#include <math.h>

// ---------------------------------------------------------------------------
// NTXentLoss fused: normalize -> (G G^T) MFMA GEMM with fused row sum(exp) ->
// log + picked + mean.  B=4096, D=256, TEMP=0.5, loss = mean(lse - picked).
// logits = dot(g_i, g_j) with g = f * sqrt(2)/||f||  (sqrt(1/TEMP) per side).
// Diagonal of logits == 2 is in every row => sum(exp) is fp32-safe, no max.
// ---------------------------------------------------------------------------

#define B_ROWS 4096
#define D_DIM  256
#define N_ROWS 8192
#define BM     128
#define BN     64
#define NCHUNK 8
#define CHUNK_COLS (N_ROWS / NCHUNK)        // 1024
#define TILES_PER_CHUNK (CHUNK_COLS / BN)   // 16

typedef __attribute__((ext_vector_type(8))) short short8;
typedef __attribute__((ext_vector_type(4))) float f32x4;

__device__ __forceinline__ float bf2f(unsigned short u) {
  union { unsigned int i; float f; } p; p.i = ((unsigned int)u) << 16; return p.f;
}

// ---------------- kernel 1: fp32 -> normalized bf16 rows -------------------
__global__ __launch_bounds__(256) void nt_normalize(const float* __restrict__ f1,
                                                    const float* __restrict__ f2,
                                                    unsigned short* __restrict__ G) {
  const int row  = blockIdx.x * 4 + (threadIdx.x >> 6);
  const int lane = threadIdx.x & 63;
  const float* src = (row < B_ROWS) ? (f1 + (size_t)row * D_DIM)
                                    : (f2 + (size_t)(row - B_ROWS) * D_DIM);
  float4 v = reinterpret_cast<const float4*>(src)[lane];
  float ss = v.x * v.x + v.y * v.y + v.z * v.z + v.w * v.w;
#pragma unroll
  for (int m = 1; m < 64; m <<= 1) ss += __shfl_xor(ss, m, 64);
  // scale = sqrt(2)/||f||   (norm ~16 for N(0,1) D=256; EPS guard never binds)
  float scale = 1.41421356237309515f * rsqrtf(fmaxf(ss, 1e-30f));
  union { ushort4 u; __hip_bfloat16 h[4]; } p;
  p.h[0] = __float2bfloat16(v.x * scale);
  p.h[1] = __float2bfloat16(v.y * scale);
  p.h[2] = __float2bfloat16(v.z * scale);
  p.h[3] = __float2bfloat16(v.w * scale);
  reinterpret_cast<ushort4*>(G + (size_t)row * D_DIM)[lane] = p.u;
}

// ---------------- kernel 2: picked[i] = dot(g_i, g_label(i)) ---------------
__global__ __launch_bounds__(256) void nt_picked(const unsigned short* __restrict__ G,
                                                 float* __restrict__ picked) {
  const int row  = blockIdx.x * 4 + (threadIdx.x >> 6);
  const int lane = threadIdx.x & 63;
  const int lbl  = (row < B_ROWS) ? row : (row - B_ROWS);
  ushort4 a = reinterpret_cast<const ushort4*>(G + (size_t)row * D_DIM)[lane];
  ushort4 b = reinterpret_cast<const ushort4*>(G + (size_t)lbl * D_DIM)[lane];
  float s = bf2f(a.x) * bf2f(b.x) + bf2f(a.y) * bf2f(b.y) +
            bf2f(a.z) * bf2f(b.z) + bf2f(a.w) * bf2f(b.w);
#pragma unroll
  for (int m = 1; m < 64; m <<= 1) s += __shfl_xor(s, m, 64);
  if (lane == 0) picked[row] = s;
}

// ------------- staging helper: contiguous global -> LDS, swizzled ----------
// LDS[o] = G[base + swz(o)], swz(o) = o ^ (((o>>9)&7)<<4)  (row stride 512 B).
// global_load_lds: per-lane GLOBAL addr, wave-uniform LDS base + lane*16.
__device__ __forceinline__ void stage_lds(const char* gsrc_base, char* lds_base,
                                          int rounds, int tid) {
  const int lane = tid & 63, wid = tid >> 6;
  for (int r = 0; r < rounds; ++r) {
    const int o  = r * 4096 + wid * 1024 + lane * 16;
    const int so = o ^ (((o >> 9) & 7) << 4);
    __builtin_amdgcn_global_load_lds(
        (const __attribute__((address_space(1))) void*)(gsrc_base + so),
        (__attribute__((address_space(3))) void*)(lds_base + r * 4096 + wid * 1024),
        16, 0, 0);
  }
}

// -------- kernel 3: fused GEMM (G G^T) + per-row sum(exp(logits)) ----------
// grid = 64 row-blocks * NCHUNK col-chunks; block = 256 (4 waves, 2x2).
// Wave tile 64x32.  A (128x256) staged once, fragments held in registers.
// B tiles (64x256 = 32 KB) double-buffered in LDS, XOR-swizzled.
__global__ __launch_bounds__(256, 2) void nt_gemm_rowsum(
    const unsigned short* __restrict__ G,
    float* __restrict__ partial)   // [NCHUNK][N_ROWS]
{
  const int bid   = blockIdx.x;
  const int rb    = bid / NCHUNK;
  const int chunk = bid % NCHUNK;
  const int tid   = threadIdx.x;
  const int lane  = tid & 63;
  const int wid   = tid >> 6;
  const int wr    = wid >> 1;      // 0..1 : row half (64 rows)
  const int wc    = wid & 1;       // 0..1 : col half (32 cols)

  __shared__ short8 lds8[4096];    // 64 KB: A stage, then B double buffer
  char* ldsb = reinterpret_cast<char*>(lds8);
  const char* gbytes = reinterpret_cast<const char*>(G);

  // ---- stage A panel (rows rb*128..+128, 64 KB contiguous) ----
  stage_lds(gbytes + (size_t)rb * BM * D_DIM * 2, ldsb, 16, tid);
  __syncthreads();

  // ---- A fragments -> registers: afrag[m][ks], row = wr*64+m*16+(lane&15),
  //      k bytes = ks*64 + (lane>>4)*16, swizzle ^((row&7)<<4) ----
  short8 afrag[4][8];
  {
    const int r0 = wr * 64;
#pragma unroll
    for (int m = 0; m < 4; ++m) {
      const int row = r0 + m * 16 + (lane & 15);
      const int sw  = (row & 7) << 4;
#pragma unroll
      for (int ks = 0; ks < 8; ++ks) {
        const int off = (row * 512 + ks * 64 + ((lane >> 4) << 4)) ^ sw;
        afrag[m][ks] = *reinterpret_cast<const short8*>(ldsb + off);
      }
    }
  }
  __syncthreads();   // all A reads done before B staging overwrites LDS

  float rowsum[16];
#pragma unroll
  for (int i = 0; i < 16; ++i) rowsum[i] = 0.f;

  const size_t colbase = (size_t)chunk * CHUNK_COLS;

  // prologue: stage B tile 0 into buffer 0
  stage_lds(gbytes + (colbase + 0) * 512, ldsb, 8, tid);
  __syncthreads();

  for (int t = 0; t < TILES_PER_CHUNK; ++t) {
    const int cur = t & 1;
    if (t + 1 < TILES_PER_CHUNK)   // prefetch next tile into other buffer
      stage_lds(gbytes + (colbase + (size_t)(t + 1) * BN) * 512,
                ldsb + ((t + 1) & 1) * 32768, 8, tid);

    char* bbuf = ldsb + cur * 32768;
    f32x4 acc[4][2] = {};
#pragma unroll
    for (int ks = 0; ks < 8; ++ks) {
      short8 bfrag[2];
#pragma unroll
      for (int n = 0; n < 2; ++n) {
        const int brow = wc * 32 + n * 16 + (lane & 15);   // tile-local col
        const int off  = (brow * 512 + ks * 64 + ((lane >> 4) << 4)) ^ ((brow & 7) << 4);
        bfrag[n] = *reinterpret_cast<const short8*>(bbuf + off);
      }
#pragma unroll
      for (int m = 0; m < 4; ++m)
#pragma unroll
        for (int n = 0; n < 2; ++n)
          acc[m][n] = __builtin_amdgcn_mfma_f32_16x16x32_bf16(
              afrag[m][ks], bfrag[n], acc[m][n], 0, 0, 0);
    }
    // epilogue: accumulate exp(logits) per row (row = m*16+(lane>>4)*4+j)
#pragma unroll
    for (int m = 0; m < 4; ++m)
#pragma unroll
      for (int n = 0; n < 2; ++n)
#pragma unroll
        for (int j = 0; j < 4; ++j)
          rowsum[m * 4 + j] += __expf(acc[m][n][j]);
    __syncthreads();   // B[t+1] resident; all reads of buf cur done
  }

  // ---- reduce: 16 lanes (lane&15) share the same 16 rows ----
#pragma unroll
  for (int i = 0; i < 16; ++i) {
    float s = rowsum[i];
    s += __shfl_xor(s, 1, 64);
    s += __shfl_xor(s, 2, 64);
    s += __shfl_xor(s, 4, 64);
    s += __shfl_xor(s, 8, 64);
    rowsum[i] = s;
  }
  __syncthreads();                       // done with B buffers, reuse LDS
  float* red = reinterpret_cast<float*>(ldsb);   // [2][128]
  if ((lane & 15) == 0) {
    const int g = lane >> 4;
#pragma unroll
    for (int i = 0; i < 16; ++i) {
      const int m = i >> 2, j = i & 3;
      red[wc * 128 + wr * 64 + m * 16 + g * 4 + j] = rowsum[i];
    }
  }
  __syncthreads();
  if (tid < 128) {
    const float s = red[tid] + red[128 + tid];
    partial[(size_t)chunk * N_ROWS + (size_t)rb * BM + tid] = s;
  }
}

// ---------------- kernel 4: loss = mean(log(sum) - picked) -----------------
__global__ __launch_bounds__(1024) void nt_finalize(const float* __restrict__ partial,
                                                    const float* __restrict__ picked,
                                                    float* __restrict__ out) {
  __shared__ float red[16];
  const int tid = threadIdx.x;
  float local = 0.f;
  for (int r = tid; r < N_ROWS; r += 1024) {
    float s = 0.f;
#pragma unroll
    for (int c = 0; c < NCHUNK; ++c) s += partial[(size_t)c * N_ROWS + r];
    local += __logf(s) - picked[r];
  }
#pragma unroll
  for (int m = 1; m < 64; m <<= 1) local += __shfl_xor(local, m, 64);
  if ((tid & 63) == 0) red[tid >> 6] = local;
  __syncthreads();
  if (tid < 64) {
    float v = (tid < 16) ? red[tid] : 0.f;
#pragma unroll
    for (int m = 1; m < 16; m <<= 1) v += __shfl_xor(v, m, 64);
    if (tid == 0) out[0] = v / (float)N_ROWS;
  }
}

// ---------------------------------------------------------------------------
extern "C" void kernel_launch(void* const* d_in, const int* in_sizes, int n_in,
                              void* d_out, int out_size, void* d_ws, size_t ws_size,
                              hipStream_t stream) {
  const float* f1 = (const float*)d_in[0];
  const float* f2 = (const float*)d_in[1];
  float* out = (float*)d_out;

  char* ws = (char*)d_ws;
  unsigned short* G = (unsigned short*)ws;                       // 4 MB bf16
  float* partial = (float*)(ws + (size_t)4 * 1024 * 1024);       // 256 KB
  float* picked  = (float*)(ws + (size_t)4 * 1024 * 1024 + 256 * 1024);  // 32 KB

  hipLaunchKernelGGL(nt_normalize, dim3(N_ROWS / 4), dim3(256), 0, stream, f1, f2, G);
  hipLaunchKernelGGL(nt_picked,    dim3(N_ROWS / 4), dim3(256), 0, stream, G, picked);
  hipLaunchKernelGGL(nt_gemm_rowsum, dim3((N_ROWS / BM) * NCHUNK), dim3(256), 0, stream,
                     G, partial);
  hipLaunchKernelGGL(nt_finalize, dim3(1), dim3(1024), 0, stream, partial, picked, out);
}